// Round 1
// baseline (1511.330 us; speedup 1.0000x reference)
//
#include <hip/hip_runtime.h>

#define NN 100000
#define NE 1600000
#define TPB 256

// ---------------------------------------------------------------- CSR build
__global__ void k_init(int* __restrict__ deg, int* __restrict__ cursor, int* __restrict__ counter) {
    int i = blockIdx.x * TPB + threadIdx.x;
    if (i < NN) { deg[i] = 0; cursor[i] = 0; }
    if (i == 0) counter[0] = 0;
}

__global__ void k_deg(const int* __restrict__ dst, int* __restrict__ deg) {
    int e = blockIdx.x * TPB + threadIdx.x;
    if (e < NE) atomicAdd(&deg[dst[e]], 1);
}

__global__ void k_prep(const int* __restrict__ deg, float* __restrict__ inv_deg,
                       float* __restrict__ dinv, int* __restrict__ row_start,
                       int* __restrict__ counter) {
    int i = blockIdx.x * TPB + threadIdx.x;
    if (i < NN) {
        int d = deg[i];
        inv_deg[i] = d > 0 ? 1.0f / (float)d : 0.0f;
        dinv[i]    = d > 0 ? 1.0f / sqrtf((float)d) : 0.0f;
        row_start[i] = atomicAdd(counter, d);
    }
}

__global__ void k_fill(const int* __restrict__ src, const int* __restrict__ dst,
                       const int* __restrict__ row_start, int* __restrict__ cursor,
                       int* __restrict__ col) {
    int e = blockIdx.x * TPB + threadIdx.x;
    if (e < NE) {
        int d = dst[e];
        int p = atomicAdd(&cursor[d], 1);
        col[row_start[d] + p] = src[e];
    }
}

// ---------------------------------------------------------------- propagation
// mean aggregation, 8 features: thread per (node, feat)
__global__ void k_meanprop8(const float* __restrict__ h, const int* __restrict__ row_start,
                            const int* __restrict__ deg, const float* __restrict__ inv_deg,
                            const int* __restrict__ col, float* __restrict__ out) {
    int t = blockIdx.x * TPB + threadIdx.x;
    if (t >= NN * 8) return;
    int n = t >> 3, f = t & 7;
    int rs = row_start[n], d = deg[n];
    float s = 0.f;
    for (int e = rs; e < rs + d; ++e) s += h[col[e] * 8 + f];
    out[t] = s * inv_deg[n];
}

// sym-normalized propagation, 8 features
__global__ void k_symprop8(const float* __restrict__ h, const int* __restrict__ row_start,
                           const int* __restrict__ deg, const float* __restrict__ dinv,
                           const int* __restrict__ col, float* __restrict__ out) {
    int t = blockIdx.x * TPB + threadIdx.x;
    if (t >= NN * 8) return;
    int n = t >> 3, f = t & 7;
    int rs = row_start[n], d = deg[n];
    float s = 0.f;
    for (int e = rs; e < rs + d; ++e) {
        int c = col[e];
        s += h[c * 8 + f] * dinv[c];
    }
    out[t] = s * dinv[n];
}

// mean aggregation, 128 features: thread per (node, feat)
__global__ void k_meanprop128(const float* __restrict__ h, const int* __restrict__ row_start,
                              const int* __restrict__ deg, const float* __restrict__ inv_deg,
                              const int* __restrict__ col, float* __restrict__ out) {
    int t = blockIdx.x * TPB + threadIdx.x;
    if (t >= NN * 128) return;
    int n = t >> 7, f = t & 127;
    int rs = row_start[n], d = deg[n];
    float s = 0.f;
    for (int e = rs; e < rs + d; ++e) s += h[col[e] * 128 + f];
    out[t] = s * inv_deg[n];
}

// sym-normalized scalar propagation + add + optional bias/relu (Horner step)
// 4 threads per node, strided edge split, shfl reduce
__global__ void k_symprop1(const float* __restrict__ tin, const float* __restrict__ yk,
                           const int* __restrict__ row_start, const int* __restrict__ deg,
                           const float* __restrict__ dinv, const int* __restrict__ col,
                           float* __restrict__ tout, const float* __restrict__ biasp,
                           int do_final) {
    int t = blockIdx.x * TPB + threadIdx.x;
    if (t >= NN * 4) return;
    int n = t >> 2, q = t & 3;
    int rs = row_start[n], d = deg[n];
    float s = 0.f;
    for (int e = rs + q; e < rs + d; e += 4) {
        int c = col[e];
        s += tin[c] * dinv[c];
    }
    s += __shfl_xor(s, 1, 64);
    s += __shfl_xor(s, 2, 64);
    if (q == 0) {
        float v = s * dinv[n] + yk[n];
        if (do_final) v = fmaxf(v + biasp[0], 0.f);
        tout[n] = v;
    }
}

// mean scalar propagation + SAGE3 epilogue: x1f = relu(agg*inv_deg + yr + b3)
__global__ void k_sage3(const float* __restrict__ yl, const float* __restrict__ yr,
                        const int* __restrict__ row_start, const int* __restrict__ deg,
                        const float* __restrict__ inv_deg, const int* __restrict__ col,
                        const float* __restrict__ b3, float* __restrict__ x1f) {
    int t = blockIdx.x * TPB + threadIdx.x;
    if (t >= NN * 4) return;
    int n = t >> 2, q = t & 3;
    int rs = row_start[n], d = deg[n];
    float s = 0.f;
    for (int e = rs + q; e < rs + d; e += 4) s += yl[col[e]];
    s += __shfl_xor(s, 1, 64);
    s += __shfl_xor(s, 2, 64);
    if (q == 0) x1f[n] = fmaxf(s * inv_deg[n] + yr[n] + b3[0], 0.f);
}

// ---------------------------------------------------------------- dense transforms
// SAGE1: x1 = relu(a8@W1l + x@W1r + b1), K=8, thread computes 8 outs of one node
__global__ void k_sage1(const float* __restrict__ a8, const float* __restrict__ x,
                        const float* __restrict__ W1l, const float* __restrict__ W1r,
                        const float* __restrict__ b1, float* __restrict__ x1) {
    int t = blockIdx.x * TPB + threadIdx.x;
    if (t >= NN * 16) return;
    int n = t >> 4, og = (t & 15) * 8;
    float acc[8];
    #pragma unroll
    for (int j = 0; j < 8; ++j) acc[j] = b1[og + j];
    const float* ar = a8 + (size_t)n * 8;
    const float* xr = x + (size_t)n * 8;
    #pragma unroll
    for (int k = 0; k < 8; ++k) {
        float av = ar[k], xv = xr[k];
        const float4* wl = (const float4*)(W1l + k * 128 + og);
        const float4* wr = (const float4*)(W1r + k * 128 + og);
        float4 l0 = wl[0], l1 = wl[1], r0 = wr[0], r1 = wr[1];
        acc[0] += av * l0.x + xv * r0.x;
        acc[1] += av * l0.y + xv * r0.y;
        acc[2] += av * l0.z + xv * r0.z;
        acc[3] += av * l0.w + xv * r0.w;
        acc[4] += av * l1.x + xv * r1.x;
        acc[5] += av * l1.y + xv * r1.y;
        acc[6] += av * l1.z + xv * r1.z;
        acc[7] += av * l1.w + xv * r1.w;
    }
    #pragma unroll
    for (int j = 0; j < 8; ++j)
        x1[(size_t)n * 128 + og + j] = fmaxf(acc[j], 0.f);
}

// SAGE2: x1b = relu(a128@W2l + x1@W2r + b2), K=128
__global__ void k_sage2(const float* __restrict__ a128, const float* __restrict__ x1,
                        const float* __restrict__ W2l, const float* __restrict__ W2r,
                        const float* __restrict__ b2, float* __restrict__ x1b) {
    int t = blockIdx.x * TPB + threadIdx.x;
    if (t >= NN * 16) return;
    int n = t >> 4, og = (t & 15) * 8;
    float acc[8];
    #pragma unroll
    for (int j = 0; j < 8; ++j) acc[j] = b2[og + j];
    const float* ar = a128 + (size_t)n * 128;
    for (int k = 0; k < 128; ++k) {
        float av = ar[k];
        const float4* w = (const float4*)(W2l + k * 128 + og);
        float4 w0 = w[0], w1 = w[1];
        acc[0] += av * w0.x; acc[1] += av * w0.y; acc[2] += av * w0.z; acc[3] += av * w0.w;
        acc[4] += av * w1.x; acc[5] += av * w1.y; acc[6] += av * w1.z; acc[7] += av * w1.w;
    }
    const float* xr = x1 + (size_t)n * 128;
    for (int k = 0; k < 128; ++k) {
        float xv = xr[k];
        const float4* w = (const float4*)(W2r + k * 128 + og);
        float4 w0 = w[0], w1 = w[1];
        acc[0] += xv * w0.x; acc[1] += xv * w0.y; acc[2] += xv * w0.z; acc[3] += xv * w0.w;
        acc[4] += xv * w1.x; acc[5] += xv * w1.y; acc[6] += xv * w1.z; acc[7] += xv * w1.w;
    }
    #pragma unroll
    for (int j = 0; j < 8; ++j)
        x1b[(size_t)n * 128 + og + j] = fmaxf(acc[j], 0.f);
}

// SAGE3 pre-multiply: yl = x1b@W3l, yr = x1b@W3r (wave per node, shfl reduce)
__global__ void k_dots(const float* __restrict__ x1b, const float* __restrict__ W3l,
                       const float* __restrict__ W3r, float* __restrict__ yl,
                       float* __restrict__ yr) {
    int t = blockIdx.x * TPB + threadIdx.x;
    if (t >= NN * 64) return;
    int n = t >> 6, l = t & 63;
    float v0 = x1b[(size_t)n * 128 + l];
    float v1 = x1b[(size_t)n * 128 + 64 + l];
    float pl = v0 * W3l[l] + v1 * W3l[64 + l];
    float pr = v0 * W3r[l] + v1 * W3r[64 + l];
    #pragma unroll
    for (int o = 1; o < 64; o <<= 1) {
        pl += __shfl_xor(pl, o, 64);
        pr += __shfl_xor(pr, o, 64);
    }
    if (l == 0) { yl[n] = pl; yr[n] = pr; }
}

// TAG k=0 term for both branches: outa = x@TaW[0], outb = x@TbW[0]
__global__ void k_taginit(const float* __restrict__ x, const float* __restrict__ TaW,
                          const float* __restrict__ TbW, float* __restrict__ outa,
                          float* __restrict__ outb) {
    int t = blockIdx.x * TPB + threadIdx.x;
    if (t >= NN * 8) return;
    int n = t >> 3, o = t & 7;
    const float* xr = x + (size_t)n * 8;
    float sa = 0.f, sb = 0.f;
    #pragma unroll
    for (int j = 0; j < 8; ++j) {
        float v = xr[j];
        sa += v * TaW[j * 8 + o];
        sb += v * TbW[j * 8 + o];
    }
    outa[t] = sa;
    outb[t] = sb;
}

// accumulate h@Wa into outa (if Wa) and h@Wb into outb
__global__ void k_tagaccum(const float* __restrict__ h, const float* __restrict__ Wa,
                           const float* __restrict__ Wb, float* __restrict__ outa,
                           float* __restrict__ outb) {
    int t = blockIdx.x * TPB + threadIdx.x;
    if (t >= NN * 8) return;
    int n = t >> 3, o = t & 7;
    const float* hr = h + (size_t)n * 8;
    float sa = 0.f, sb = 0.f;
    #pragma unroll
    for (int j = 0; j < 8; ++j) {
        float v = hr[j];
        if (Wa) sa += v * Wa[j * 8 + o];
        sb += v * Wb[j * 8 + o];
    }
    if (Wa) outa[t] += sa;
    outb[t] += sb;
}

__global__ void k_relubias8(float* __restrict__ buf, const float* __restrict__ b) {
    int t = blockIdx.x * TPB + threadIdx.x;
    if (t >= NN * 8) return;
    buf[t] = fmaxf(buf[t] + b[t & 7], 0.f);
}

// project 8-wide features through K1 (8x1) matrices: y[k][n] = h8[n]·W[k]
__global__ void k_tag2proj(const float* __restrict__ h8, const float* __restrict__ W,
                           float* __restrict__ y, int K1) {
    int n = blockIdx.x * TPB + threadIdx.x;
    if (n >= NN) return;
    float hr[8];
    #pragma unroll
    for (int j = 0; j < 8; ++j) hr[j] = h8[(size_t)n * 8 + j];
    for (int k = 0; k < K1; ++k) {
        float s = 0.f;
        #pragma unroll
        for (int j = 0; j < 8; ++j) s += hr[j] * W[k * 8 + j];
        y[(size_t)k * NN + n] = s;
    }
}

// final: x23 = relu(x2*l2w0 + x3*l2w1 + l2b); out = relu(x1f*l1w0 + x23*l1w1 + l1b)
__global__ void k_final(const float* __restrict__ x1f, const float* __restrict__ x2s,
                        const float* __restrict__ x3s, const float* __restrict__ l2w,
                        const float* __restrict__ l2b, const float* __restrict__ l1w,
                        const float* __restrict__ l1b, float* __restrict__ out) {
    int n = blockIdx.x * TPB + threadIdx.x;
    if (n >= NN) return;
    float x23 = fmaxf(x2s[n] * l2w[0] + x3s[n] * l2w[1] + l2b[0], 0.f);
    out[n] = fmaxf(x1f[n] * l1w[0] + x23 * l1w[1] + l1b[0], 0.f);
}

// ---------------------------------------------------------------- host launch
#define GL(kern, n, ...) \
    kern<<<dim3((unsigned)(((long)(n) + TPB - 1) / TPB)), dim3(TPB), 0, stream>>>(__VA_ARGS__)

extern "C" void kernel_launch(void* const* d_in, const int* in_sizes, int n_in,
                              void* d_out, int out_size, void* d_ws, size_t ws_size,
                              hipStream_t stream) {
    (void)in_sizes; (void)n_in; (void)out_size; (void)ws_size;
    const float* x   = (const float*)d_in[0];
    const int*   ei  = (const int*)d_in[1];
    const int*   src = ei;
    const int*   dst = ei + NE;
    const float* W1l = (const float*)d_in[2];
    const float* W1r = (const float*)d_in[3];
    const float* b1  = (const float*)d_in[4];
    const float* W2l = (const float*)d_in[5];
    const float* W2r = (const float*)d_in[6];
    const float* b2  = (const float*)d_in[7];
    const float* W3l = (const float*)d_in[8];
    const float* W3r = (const float*)d_in[9];
    const float* b3  = (const float*)d_in[10];
    const float* TaW1 = (const float*)d_in[11];
    const float* TaB1 = (const float*)d_in[12];
    const float* TaW2 = (const float*)d_in[13];
    const float* TaB2 = (const float*)d_in[14];
    const float* TbW1 = (const float*)d_in[15];
    const float* TbB1 = (const float*)d_in[16];
    const float* TbW2 = (const float*)d_in[17];
    const float* TbB2 = (const float*)d_in[18];
    const float* l2w = (const float*)d_in[19];
    const float* l2b = (const float*)d_in[20];
    const float* l1w = (const float*)d_in[21];
    const float* l1b = (const float*)d_in[22];
    float* out = (float*)d_out;

    char* p = (char*)d_ws;
    size_t off = 0;
    auto alloc = [&](size_t bytes) -> void* {
        void* r = p + off;
        off = (off + bytes + 255) & ~(size_t)255;
        return r;
    };
    int*   deg       = (int*)  alloc((size_t)NN * 4);
    float* inv_deg   = (float*)alloc((size_t)NN * 4);
    float* dinv      = (float*)alloc((size_t)NN * 4);
    int*   row_start = (int*)  alloc((size_t)NN * 4);
    int*   cursor    = (int*)  alloc((size_t)NN * 4);
    int*   counter   = (int*)  alloc(256);
    int*   col       = (int*)  alloc((size_t)NE * 4);
    float* a8        = (float*)alloc((size_t)NN * 8 * 4);
    float* h8a       = (float*)alloc((size_t)NN * 8 * 4);
    float* h8b       = (float*)alloc((size_t)NN * 8 * 4);
    float* outa      = (float*)alloc((size_t)NN * 8 * 4);
    float* outb      = (float*)alloc((size_t)NN * 8 * 4);
    float* x1        = (float*)alloc((size_t)NN * 128 * 4);
    float* a128      = (float*)alloc((size_t)NN * 128 * 4);
    float* x1b       = (float*)alloc((size_t)NN * 128 * 4);
    float* yl        = (float*)alloc((size_t)NN * 4);
    float* yr        = (float*)alloc((size_t)NN * 4);
    float* x1f       = (float*)alloc((size_t)NN * 4);
    float* x2s       = (float*)alloc((size_t)NN * 4);
    float* x3s       = (float*)alloc((size_t)NN * 4);
    float* tA        = (float*)alloc((size_t)NN * 4);
    float* tB        = (float*)alloc((size_t)NN * 4);
    float* ya        = (float*)alloc((size_t)NN * 4 * 4);
    float* yb        = (float*)alloc((size_t)NN * 10 * 4);

    // CSR build (reused by all 13 edge passes)
    GL(k_init, NN, deg, cursor, counter);
    GL(k_deg, NE, dst, deg);
    GL(k_prep, NN, deg, inv_deg, dinv, row_start, counter);
    GL(k_fill, NE, src, dst, row_start, cursor, col);

    // SAGE1
    GL(k_meanprop8, (long)NN * 8, x, row_start, deg, inv_deg, col, a8);
    GL(k_sage1, (long)NN * 16, a8, x, W1l, W1r, b1, x1);
    // SAGE2
    GL(k_meanprop128, (long)NN * 128, x1, row_start, deg, inv_deg, col, a128);
    GL(k_sage2, (long)NN * 16, a128, x1, W2l, W2r, b2, x1b);
    // SAGE3 (pre-multiplied scalar propagation)
    GL(k_dots, (long)NN * 64, x1b, W3l, W3r, yl, yr);
    GL(k_sage3, (long)NN * 4, yl, yr, row_start, deg, inv_deg, col, b3, x1f);

    // TAG layer 1 — shared P^k x chain feeds both branches
    GL(k_taginit, (long)NN * 8, x, TaW1, TbW1, outa, outb);
    const float* hin = x;
    float* hbufs[2] = { h8a, h8b };
    for (int k = 1; k <= 9; ++k) {
        float* hout = hbufs[(k - 1) & 1];
        GL(k_symprop8, (long)NN * 8, hin, row_start, deg, dinv, col, hout);
        const float* Wa = (k <= 3) ? (TaW1 + (size_t)k * 64) : nullptr;
        GL(k_tagaccum, (long)NN * 8, hout, Wa, TbW1 + (size_t)k * 64, outa, outb);
        hin = hout;
    }
    GL(k_relubias8, (long)NN * 8, outa, TaB1);  // outa -> x2 (8-wide)
    GL(k_relubias8, (long)NN * 8, outb, TbB1);  // outb -> x3 (8-wide)

    // TAGa layer 2 (K=3): project then Horner with scalar propagations
    GL(k_tag2proj, NN, outa, TaW2, ya, 4);
    GL(k_symprop1, (long)NN * 4, ya + 3 * NN, ya + 2 * NN, row_start, deg, dinv, col, tA, TaB2, 0);
    GL(k_symprop1, (long)NN * 4, tA, ya + 1 * NN, row_start, deg, dinv, col, tB, TaB2, 0);
    GL(k_symprop1, (long)NN * 4, tB, ya + 0 * NN, row_start, deg, dinv, col, x2s, TaB2, 1);

    // TAGb layer 2 (K=9): same, 9 scalar propagations
    GL(k_tag2proj, NN, outb, TbW2, yb, 10);
    {
        const float* tprev = yb + 9 * NN;
        for (int k = 8; k >= 1; --k) {
            float* tout = (k & 1) ? tA : tB;
            GL(k_symprop1, (long)NN * 4, tprev, yb + (size_t)k * NN, row_start, deg, dinv, col, tout, TbB2, 0);
            tprev = tout;
        }
        GL(k_symprop1, (long)NN * 4, tprev, yb + 0 * NN, row_start, deg, dinv, col, x3s, TbB2, 1);
    }

    // final combine
    GL(k_final, NN, x1f, x2s, x3s, l2w, l2b, l1w, l1b, out);
}

// Round 2
// 1095.151 us; speedup vs baseline: 1.3800x; 1.3800x over previous
//
#include <hip/hip_runtime.h>

#define NN 100000
#define NE 1600000
#define TPB 256

// ---------------------------------------------------------------- CSR build
__global__ void k_init(int* __restrict__ deg, int* __restrict__ cursor, int* __restrict__ counter) {
    int i = blockIdx.x * TPB + threadIdx.x;
    if (i < NN) { deg[i] = 0; cursor[i] = 0; }
    if (i == 0) counter[0] = 0;
}

__global__ void k_deg(const int* __restrict__ dst, int* __restrict__ deg) {
    int e = blockIdx.x * TPB + threadIdx.x;
    if (e < NE) atomicAdd(&deg[dst[e]], 1);
}

__global__ void k_prep(const int* __restrict__ deg, float* __restrict__ inv_deg,
                       float* __restrict__ dinv, int* __restrict__ row_start,
                       int* __restrict__ counter) {
    int i = blockIdx.x * TPB + threadIdx.x;
    if (i < NN) {
        int d = deg[i];
        inv_deg[i] = d > 0 ? 1.0f / (float)d : 0.0f;
        dinv[i]    = d > 0 ? 1.0f / sqrtf((float)d) : 0.0f;
        row_start[i] = atomicAdd(counter, d);
    }
}

__global__ void k_fill(const int* __restrict__ src, const int* __restrict__ dst,
                       const int* __restrict__ row_start, int* __restrict__ cursor,
                       int* __restrict__ col) {
    int e = blockIdx.x * TPB + threadIdx.x;
    if (e < NE) {
        int d = dst[e];
        int p = atomicAdd(&cursor[d], 1);
        col[row_start[d] + p] = src[e];
    }
}

// ---------------------------------------------------------------- propagation
// mean aggregation, 8 features: thread per (node, feat)
__global__ void k_meanprop8(const float* __restrict__ h, const int* __restrict__ row_start,
                            const int* __restrict__ deg, const float* __restrict__ inv_deg,
                            const int* __restrict__ col, float* __restrict__ out) {
    int t = blockIdx.x * TPB + threadIdx.x;
    if (t >= NN * 8) return;
    int n = t >> 3, f = t & 7;
    int rs = row_start[n], d = deg[n];
    float s = 0.f;
    for (int e = rs; e < rs + d; ++e) s += h[col[e] * 8 + f];
    out[t] = s * inv_deg[n];
}

// mean aggregation, 128 features: thread per (node, 4 feats), float4 gather
__global__ void k_meanprop128(const float* __restrict__ h, const int* __restrict__ row_start,
                              const int* __restrict__ deg, const float* __restrict__ inv_deg,
                              const int* __restrict__ col, float* __restrict__ out) {
    int t = blockIdx.x * TPB + threadIdx.x;
    if (t >= NN * 32) return;
    int n = t >> 5, f4 = t & 31;
    int rs = row_start[n], d = deg[n];
    const float4* h4 = (const float4*)h;
    float4 s = make_float4(0.f, 0.f, 0.f, 0.f);
    for (int e = rs; e < rs + d; ++e) {
        int c = col[e];
        float4 v = h4[(size_t)c * 32 + f4];
        s.x += v.x; s.y += v.y; s.z += v.z; s.w += v.w;
    }
    float w = inv_deg[n];
    s.x *= w; s.y *= w; s.z *= w; s.w *= w;
    ((float4*)out)[t] = s;
}

// fused TAG layer-1 step: sym-prop 8 feats + accumulate projections into outa/outb
// thread per (node, feat); 8-lane shfl group does the feature contraction
__global__ void k_tagstep(const float* __restrict__ h, const int* __restrict__ row_start,
                          const int* __restrict__ deg, const float* __restrict__ dinv,
                          const int* __restrict__ col, float* __restrict__ hout,
                          const float* __restrict__ Wa, const float* __restrict__ Wb,
                          float* __restrict__ outa, float* __restrict__ outb,
                          const float* __restrict__ ba, const float* __restrict__ bb,
                          int fina, int finb) {
    int t = blockIdx.x * TPB + threadIdx.x;
    if (t >= NN * 8) return;
    int n = t >> 3, f = t & 7;
    int rs = row_start[n], d = deg[n];
    float s = 0.f;
    for (int e = rs; e < rs + d; ++e) {
        int c = col[e];
        s += h[c * 8 + f] * dinv[c];
    }
    s *= dinv[n];                    // propagated value P^k x at (n,f)
    if (hout) hout[t] = s;
    int base = (threadIdx.x & 63) & 56;
    float suma = 0.f, sumb = 0.f;
    #pragma unroll
    for (int j = 0; j < 8; ++j) {
        float v = __shfl(s, base + j, 64);
        if (Wa) suma += v * Wa[j * 8 + f];
        sumb += v * Wb[j * 8 + f];
    }
    if (Wa) {
        float oa = outa[t] + suma;
        if (fina) oa = fmaxf(oa + ba[f], 0.f);
        outa[t] = oa;
    }
    float ob = outb[t] + sumb;
    if (finb) ob = fmaxf(ob + bb[f], 0.f);
    outb[t] = ob;
}

// sym-normalized scalar propagation + add + optional bias/relu (Horner step)
__global__ void k_symprop1(const float* __restrict__ tin, const float* __restrict__ yk,
                           const int* __restrict__ row_start, const int* __restrict__ deg,
                           const float* __restrict__ dinv, const int* __restrict__ col,
                           float* __restrict__ tout, const float* __restrict__ biasp,
                           int do_final) {
    int t = blockIdx.x * TPB + threadIdx.x;
    if (t >= NN * 4) return;
    int n = t >> 2, q = t & 3;
    int rs = row_start[n], d = deg[n];
    float s = 0.f;
    for (int e = rs + q; e < rs + d; e += 4) {
        int c = col[e];
        s += tin[c] * dinv[c];
    }
    s += __shfl_xor(s, 1, 64);
    s += __shfl_xor(s, 2, 64);
    if (q == 0) {
        float v = s * dinv[n] + yk[n];
        if (do_final) v = fmaxf(v + biasp[0], 0.f);
        tout[n] = v;
    }
}

// mean scalar propagation + SAGE3 epilogue
__global__ void k_sage3(const float* __restrict__ yl, const float* __restrict__ yr,
                        const int* __restrict__ row_start, const int* __restrict__ deg,
                        const float* __restrict__ inv_deg, const int* __restrict__ col,
                        const float* __restrict__ b3, float* __restrict__ x1f) {
    int t = blockIdx.x * TPB + threadIdx.x;
    if (t >= NN * 4) return;
    int n = t >> 2, q = t & 3;
    int rs = row_start[n], d = deg[n];
    float s = 0.f;
    for (int e = rs + q; e < rs + d; e += 4) s += yl[col[e]];
    s += __shfl_xor(s, 1, 64);
    s += __shfl_xor(s, 2, 64);
    if (q == 0) x1f[n] = fmaxf(s * inv_deg[n] + yr[n] + b3[0], 0.f);
}

// ---------------------------------------------------------------- dense transforms
// SAGE1: x1 = relu(a8@W1l + x@W1r + b1), K=8
__global__ void k_sage1(const float* __restrict__ a8, const float* __restrict__ x,
                        const float* __restrict__ W1l, const float* __restrict__ W1r,
                        const float* __restrict__ b1, float* __restrict__ x1) {
    int t = blockIdx.x * TPB + threadIdx.x;
    if (t >= NN * 16) return;
    int n = t >> 4, og = (t & 15) * 8;
    float acc[8];
    #pragma unroll
    for (int j = 0; j < 8; ++j) acc[j] = b1[og + j];
    const float* ar = a8 + (size_t)n * 8;
    const float* xr = x + (size_t)n * 8;
    #pragma unroll
    for (int k = 0; k < 8; ++k) {
        float av = ar[k], xv = xr[k];
        const float4* wl = (const float4*)(W1l + k * 128 + og);
        const float4* wr = (const float4*)(W1r + k * 128 + og);
        float4 l0 = wl[0], l1 = wl[1], r0 = wr[0], r1 = wr[1];
        acc[0] += av * l0.x + xv * r0.x;
        acc[1] += av * l0.y + xv * r0.y;
        acc[2] += av * l0.z + xv * r0.z;
        acc[3] += av * l0.w + xv * r0.w;
        acc[4] += av * l1.x + xv * r1.x;
        acc[5] += av * l1.y + xv * r1.y;
        acc[6] += av * l1.z + xv * r1.z;
        acc[7] += av * l1.w + xv * r1.w;
    }
    #pragma unroll
    for (int j = 0; j < 8; ++j)
        x1[(size_t)n * 128 + og + j] = fmaxf(acc[j], 0.f);
}

// SAGE2 GEMM half: acc[i][:] += act[n[i]] @ W (K=128), k unrolled x4, float4 loads
__device__ __forceinline__ void gemm_half(const float* __restrict__ act,
                                          const int* __restrict__ n,
                                          const float* __restrict__ W, int og,
                                          float (&acc)[4][8]) {
    const float4* A[4];
    #pragma unroll
    for (int i = 0; i < 4; ++i) A[i] = (const float4*)(act + (size_t)n[i] * 128);
    for (int k4 = 0; k4 < 32; ++k4) {
        float av[4][4];
        #pragma unroll
        for (int i = 0; i < 4; ++i) *(float4*)av[i] = A[i][k4];
        const float* wp = W + k4 * 512 + og;
        #pragma unroll
        for (int r = 0; r < 4; ++r) {
            float4 w0 = *(const float4*)(wp + r * 128);
            float4 w1 = *(const float4*)(wp + r * 128 + 4);
            #pragma unroll
            for (int i = 0; i < 4; ++i) {
                float s = av[i][r];
                acc[i][0] += s * w0.x; acc[i][1] += s * w0.y;
                acc[i][2] += s * w0.z; acc[i][3] += s * w0.w;
                acc[i][4] += s * w1.x; acc[i][5] += s * w1.y;
                acc[i][6] += s * w1.z; acc[i][7] += s * w1.w;
            }
        }
    }
}

// SAGE2: x1b = relu(a128@W2l + x1@W2r + b2); 4 nodes x 8 outs per thread
__global__ __launch_bounds__(256) void k_sage2(const float* __restrict__ a128,
                        const float* __restrict__ x1,
                        const float* __restrict__ W2l, const float* __restrict__ W2r,
                        const float* __restrict__ b2, float* __restrict__ x1b) {
    int tid = threadIdx.x;
    int og = (tid & 15) * 8;
    int n0 = blockIdx.x * 64 + (tid >> 4) * 4;
    int n[4];
    #pragma unroll
    for (int i = 0; i < 4; ++i) n[i] = min(n0 + i, NN - 1);
    float acc[4][8];
    #pragma unroll
    for (int i = 0; i < 4; ++i)
        #pragma unroll
        for (int j = 0; j < 8; ++j) acc[i][j] = b2[og + j];
    gemm_half(a128, n, W2l, og, acc);
    gemm_half(x1, n, W2r, og, acc);
    #pragma unroll
    for (int i = 0; i < 4; ++i) {
        if (n0 + i < NN) {
            float4 o0 = make_float4(fmaxf(acc[i][0], 0.f), fmaxf(acc[i][1], 0.f),
                                    fmaxf(acc[i][2], 0.f), fmaxf(acc[i][3], 0.f));
            float4 o1 = make_float4(fmaxf(acc[i][4], 0.f), fmaxf(acc[i][5], 0.f),
                                    fmaxf(acc[i][6], 0.f), fmaxf(acc[i][7], 0.f));
            *(float4*)(x1b + (size_t)n[i] * 128 + og) = o0;
            *(float4*)(x1b + (size_t)n[i] * 128 + og + 4) = o1;
        }
    }
}

// SAGE3 pre-multiply: yl = x1b@W3l, yr = x1b@W3r (wave per node)
__global__ void k_dots(const float* __restrict__ x1b, const float* __restrict__ W3l,
                       const float* __restrict__ W3r, float* __restrict__ yl,
                       float* __restrict__ yr) {
    int t = blockIdx.x * TPB + threadIdx.x;
    if (t >= NN * 64) return;
    int n = t >> 6, l = t & 63;
    float v0 = x1b[(size_t)n * 128 + l];
    float v1 = x1b[(size_t)n * 128 + 64 + l];
    float pl = v0 * W3l[l] + v1 * W3l[64 + l];
    float pr = v0 * W3r[l] + v1 * W3r[64 + l];
    #pragma unroll
    for (int o = 1; o < 64; o <<= 1) {
        pl += __shfl_xor(pl, o, 64);
        pr += __shfl_xor(pr, o, 64);
    }
    if (l == 0) { yl[n] = pl; yr[n] = pr; }
}

// TAG k=0 term for both branches
__global__ void k_taginit(const float* __restrict__ x, const float* __restrict__ TaW,
                          const float* __restrict__ TbW, float* __restrict__ outa,
                          float* __restrict__ outb) {
    int t = blockIdx.x * TPB + threadIdx.x;
    if (t >= NN * 8) return;
    int n = t >> 3, o = t & 7;
    const float* xr = x + (size_t)n * 8;
    float sa = 0.f, sb = 0.f;
    #pragma unroll
    for (int j = 0; j < 8; ++j) {
        float v = xr[j];
        sa += v * TaW[j * 8 + o];
        sb += v * TbW[j * 8 + o];
    }
    outa[t] = sa;
    outb[t] = sb;
}

// project 8-wide features through K1 (8x1) matrices
__global__ void k_tag2proj(const float* __restrict__ h8, const float* __restrict__ W,
                           float* __restrict__ y, int K1) {
    int n = blockIdx.x * TPB + threadIdx.x;
    if (n >= NN) return;
    float hr[8];
    #pragma unroll
    for (int j = 0; j < 8; ++j) hr[j] = h8[(size_t)n * 8 + j];
    for (int k = 0; k < K1; ++k) {
        float s = 0.f;
        #pragma unroll
        for (int j = 0; j < 8; ++j) s += hr[j] * W[k * 8 + j];
        y[(size_t)k * NN + n] = s;
    }
}

// final combine
__global__ void k_final(const float* __restrict__ x1f, const float* __restrict__ x2s,
                        const float* __restrict__ x3s, const float* __restrict__ l2w,
                        const float* __restrict__ l2b, const float* __restrict__ l1w,
                        const float* __restrict__ l1b, float* __restrict__ out) {
    int n = blockIdx.x * TPB + threadIdx.x;
    if (n >= NN) return;
    float x23 = fmaxf(x2s[n] * l2w[0] + x3s[n] * l2w[1] + l2b[0], 0.f);
    out[n] = fmaxf(x1f[n] * l1w[0] + x23 * l1w[1] + l1b[0], 0.f);
}

// ---------------------------------------------------------------- host launch
#define GL(kern, n, ...) \
    kern<<<dim3((unsigned)(((long)(n) + TPB - 1) / TPB)), dim3(TPB), 0, stream>>>(__VA_ARGS__)

extern "C" void kernel_launch(void* const* d_in, const int* in_sizes, int n_in,
                              void* d_out, int out_size, void* d_ws, size_t ws_size,
                              hipStream_t stream) {
    (void)in_sizes; (void)n_in; (void)out_size; (void)ws_size;
    const float* x   = (const float*)d_in[0];
    const int*   ei  = (const int*)d_in[1];
    const int*   src = ei;
    const int*   dst = ei + NE;
    const float* W1l = (const float*)d_in[2];
    const float* W1r = (const float*)d_in[3];
    const float* b1  = (const float*)d_in[4];
    const float* W2l = (const float*)d_in[5];
    const float* W2r = (const float*)d_in[6];
    const float* b2  = (const float*)d_in[7];
    const float* W3l = (const float*)d_in[8];
    const float* W3r = (const float*)d_in[9];
    const float* b3  = (const float*)d_in[10];
    const float* TaW1 = (const float*)d_in[11];
    const float* TaB1 = (const float*)d_in[12];
    const float* TaW2 = (const float*)d_in[13];
    const float* TaB2 = (const float*)d_in[14];
    const float* TbW1 = (const float*)d_in[15];
    const float* TbB1 = (const float*)d_in[16];
    const float* TbW2 = (const float*)d_in[17];
    const float* TbB2 = (const float*)d_in[18];
    const float* l2w = (const float*)d_in[19];
    const float* l2b = (const float*)d_in[20];
    const float* l1w = (const float*)d_in[21];
    const float* l1b = (const float*)d_in[22];
    float* out = (float*)d_out;

    char* p = (char*)d_ws;
    size_t off = 0;
    auto alloc = [&](size_t bytes) -> void* {
        void* r = p + off;
        off = (off + bytes + 255) & ~(size_t)255;
        return r;
    };
    int*   deg       = (int*)  alloc((size_t)NN * 4);
    float* inv_deg   = (float*)alloc((size_t)NN * 4);
    float* dinv      = (float*)alloc((size_t)NN * 4);
    int*   row_start = (int*)  alloc((size_t)NN * 4);
    int*   cursor    = (int*)  alloc((size_t)NN * 4);
    int*   counter   = (int*)  alloc(256);
    int*   col       = (int*)  alloc((size_t)NE * 4);
    float* a8        = (float*)alloc((size_t)NN * 8 * 4);
    float* h8a       = (float*)alloc((size_t)NN * 8 * 4);
    float* h8b       = (float*)alloc((size_t)NN * 8 * 4);
    float* outa      = (float*)alloc((size_t)NN * 8 * 4);
    float* outb      = (float*)alloc((size_t)NN * 8 * 4);
    float* x1        = (float*)alloc((size_t)NN * 128 * 4);
    float* a128      = (float*)alloc((size_t)NN * 128 * 4);
    float* x1b      = (float*)alloc((size_t)NN * 128 * 4);
    float* yl        = (float*)alloc((size_t)NN * 4);
    float* yr        = (float*)alloc((size_t)NN * 4);
    float* x1f       = (float*)alloc((size_t)NN * 4);
    float* x2s       = (float*)alloc((size_t)NN * 4);
    float* x3s       = (float*)alloc((size_t)NN * 4);
    float* tA        = (float*)alloc((size_t)NN * 4);
    float* tB        = (float*)alloc((size_t)NN * 4);
    float* ya        = (float*)alloc((size_t)NN * 4 * 4);
    float* yb        = (float*)alloc((size_t)NN * 10 * 4);

    // CSR build (reused by all edge passes)
    GL(k_init, NN, deg, cursor, counter);
    GL(k_deg, NE, dst, deg);
    GL(k_prep, NN, deg, inv_deg, dinv, row_start, counter);
    GL(k_fill, NE, src, dst, row_start, cursor, col);

    // SAGE1
    GL(k_meanprop8, (long)NN * 8, x, row_start, deg, inv_deg, col, a8);
    GL(k_sage1, (long)NN * 16, a8, x, W1l, W1r, b1, x1);
    // SAGE2
    GL(k_meanprop128, (long)NN * 32, x1, row_start, deg, inv_deg, col, a128);
    k_sage2<<<dim3((NN + 63) / 64), dim3(256), 0, stream>>>(a128, x1, W2l, W2r, b2, x1b);
    // SAGE3 (pre-multiplied scalar propagation)
    GL(k_dots, (long)NN * 64, x1b, W3l, W3r, yl, yr);
    GL(k_sage3, (long)NN * 4, yl, yr, row_start, deg, inv_deg, col, b3, x1f);

    // TAG layer 1 — shared P^k x chain feeds both branches, fused accumulate
    GL(k_taginit, (long)NN * 8, x, TaW1, TbW1, outa, outb);
    {
        const float* hin = x;
        float* hbufs[2] = { h8a, h8b };
        for (int k = 1; k <= 9; ++k) {
            float* hout = (k < 9) ? hbufs[(k - 1) & 1] : nullptr;
            const float* Wa = (k <= 3) ? (TaW1 + (size_t)k * 64) : nullptr;
            GL(k_tagstep, (long)NN * 8, hin, row_start, deg, dinv, col, hout,
               Wa, TbW1 + (size_t)k * 64, outa, outb, TaB1, TbB1,
               (k == 3) ? 1 : 0, (k == 9) ? 1 : 0);
            if (hout) hin = hout;
        }
    }

    // TAGa layer 2 (K=3): project then Horner with scalar propagations
    GL(k_tag2proj, NN, outa, TaW2, ya, 4);
    GL(k_symprop1, (long)NN * 4, ya + 3 * NN, ya + 2 * NN, row_start, deg, dinv, col, tA, TaB2, 0);
    GL(k_symprop1, (long)NN * 4, tA, ya + 1 * NN, row_start, deg, dinv, col, tB, TaB2, 0);
    GL(k_symprop1, (long)NN * 4, tB, ya + 0 * NN, row_start, deg, dinv, col, x2s, TaB2, 1);

    // TAGb layer 2 (K=9)
    GL(k_tag2proj, NN, outb, TbW2, yb, 10);
    {
        const float* tprev = yb + 9 * NN;
        for (int k = 8; k >= 1; --k) {
            float* tout = (k & 1) ? tA : tB;
            GL(k_symprop1, (long)NN * 4, tprev, yb + (size_t)k * NN, row_start, deg, dinv, col, tout, TbB2, 0);
            tprev = tout;
        }
        GL(k_symprop1, (long)NN * 4, tprev, yb + 0 * NN, row_start, deg, dinv, col, x3s, TbB2, 1);
    }

    // final combine
    GL(k_final, NN, x1f, x2s, x3s, l2w, l2b, l1w, l1b, out);
}

// Round 3
// 955.226 us; speedup vs baseline: 1.5822x; 1.1465x over previous
//
#include <hip/hip_runtime.h>

#define NN 100000
#define NE 1600000
#define TPB 256

// ---------------------------------------------------------------- CSR build
__global__ void k_init(int* __restrict__ deg, int* __restrict__ cursor, int* __restrict__ counter) {
    int i = blockIdx.x * TPB + threadIdx.x;
    if (i < NN) { deg[i] = 0; cursor[i] = 0; }
    if (i == 0) counter[0] = 0;
}

__global__ void k_deg(const int* __restrict__ dst, int* __restrict__ deg) {
    int e = blockIdx.x * TPB + threadIdx.x;
    if (e < NE) atomicAdd(&deg[dst[e]], 1);
}

__global__ void k_prep(const int* __restrict__ deg, float* __restrict__ inv_deg,
                       float* __restrict__ dinv, int* __restrict__ row_start,
                       int* __restrict__ counter) {
    int i = blockIdx.x * TPB + threadIdx.x;
    if (i < NN) {
        int d = deg[i];
        inv_deg[i] = d > 0 ? 1.0f / (float)d : 0.0f;
        dinv[i]    = d > 0 ? 1.0f / sqrtf((float)d) : 0.0f;
        row_start[i] = atomicAdd(counter, d);
    }
}

__global__ void k_fill(const int* __restrict__ src, const int* __restrict__ dst,
                       const int* __restrict__ row_start, int* __restrict__ cursor,
                       int* __restrict__ col) {
    int e = blockIdx.x * TPB + threadIdx.x;
    if (e < NE) {
        int d = dst[e];
        int p = atomicAdd(&cursor[d], 1);
        col[row_start[d] + p] = src[e];
    }
}

// ---------------------------------------------------------------- propagation
// mean aggregation, 8 feats: 2 threads per node, float4 gathers, shfl combine
__global__ void k_meanprop8(const float* __restrict__ h, const int* __restrict__ row_start,
                            const int* __restrict__ deg, const float* __restrict__ inv_deg,
                            const int* __restrict__ col, float* __restrict__ out) {
    int t = blockIdx.x * TPB + threadIdx.x;
    if (t >= NN * 2) return;
    int n = t >> 1, half = t & 1;
    int rs = row_start[n], end = rs + deg[n];
    const float4* h4 = (const float4*)h;
    float4 s0 = make_float4(0,0,0,0), s1 = make_float4(0,0,0,0);
    int e = rs + half;
    for (; e + 2 < end; e += 4) {
        int c0 = col[e] * 2, c1 = col[e + 2] * 2;
        float4 a0 = h4[c0], a1 = h4[c0 + 1], b0 = h4[c1], b1 = h4[c1 + 1];
        s0.x += a0.x + b0.x; s0.y += a0.y + b0.y; s0.z += a0.z + b0.z; s0.w += a0.w + b0.w;
        s1.x += a1.x + b1.x; s1.y += a1.y + b1.y; s1.z += a1.z + b1.z; s1.w += a1.w + b1.w;
    }
    if (e < end) {
        int c0 = col[e] * 2;
        float4 a0 = h4[c0], a1 = h4[c0 + 1];
        s0.x += a0.x; s0.y += a0.y; s0.z += a0.z; s0.w += a0.w;
        s1.x += a1.x; s1.y += a1.y; s1.z += a1.z; s1.w += a1.w;
    }
    s0.x += __shfl_xor(s0.x, 1, 64); s0.y += __shfl_xor(s0.y, 1, 64);
    s0.z += __shfl_xor(s0.z, 1, 64); s0.w += __shfl_xor(s0.w, 1, 64);
    s1.x += __shfl_xor(s1.x, 1, 64); s1.y += __shfl_xor(s1.y, 1, 64);
    s1.z += __shfl_xor(s1.z, 1, 64); s1.w += __shfl_xor(s1.w, 1, 64);
    float w = inv_deg[n];
    float4 o = (half == 0) ? s0 : s1;
    o.x *= w; o.y *= w; o.z *= w; o.w *= w;
    ((float4*)out)[n * 2 + half] = o;
}

// mean aggregation, 128 feats: thread per (node, 4 feats), float4 gather
__global__ void k_meanprop128(const float* __restrict__ h, const int* __restrict__ row_start,
                              const int* __restrict__ deg, const float* __restrict__ inv_deg,
                              const int* __restrict__ col, float* __restrict__ out) {
    int t = blockIdx.x * TPB + threadIdx.x;
    if (t >= NN * 32) return;
    int n = t >> 5, f4 = t & 31;
    int rs = row_start[n], d = deg[n];
    const float4* h4 = (const float4*)h;
    float4 s = make_float4(0.f, 0.f, 0.f, 0.f);
    for (int e = rs; e < rs + d; ++e) {
        int c = col[e];
        float4 v = h4[(size_t)c * 32 + f4];
        s.x += v.x; s.y += v.y; s.z += v.z; s.w += v.w;
    }
    float w = inv_deg[n];
    s.x *= w; s.y *= w; s.z *= w; s.w *= w;
    ((float4*)out)[t] = s;
}

// fused TAG layer-1 step: 2 threads/node, q-prescaled gather (q = dinv[n]*h[n]),
// writes q_next and accumulates projections h@Wa / h@Wb into outa/outb.
__global__ void k_tagstep(const float* __restrict__ q, const int* __restrict__ row_start,
                          const int* __restrict__ deg, const float* __restrict__ dinv,
                          const int* __restrict__ col, float* __restrict__ qout,
                          const float* __restrict__ Wa, const float* __restrict__ Wb,
                          float* __restrict__ outa, float* __restrict__ outb,
                          const float* __restrict__ ba, const float* __restrict__ bb,
                          int fina, int finb) {
    int t = blockIdx.x * TPB + threadIdx.x;
    if (t >= NN * 2) return;
    int n = t >> 1, half = t & 1;
    int rs = row_start[n], end = rs + deg[n];
    const float4* q4 = (const float4*)q;
    float4 s0 = make_float4(0,0,0,0), s1 = make_float4(0,0,0,0);
    int e = rs + half;
    for (; e + 2 < end; e += 4) {
        int c0 = col[e] * 2, c1 = col[e + 2] * 2;
        float4 a0 = q4[c0], a1 = q4[c0 + 1], b0 = q4[c1], b1 = q4[c1 + 1];
        s0.x += a0.x + b0.x; s0.y += a0.y + b0.y; s0.z += a0.z + b0.z; s0.w += a0.w + b0.w;
        s1.x += a1.x + b1.x; s1.y += a1.y + b1.y; s1.z += a1.z + b1.z; s1.w += a1.w + b1.w;
    }
    if (e < end) {
        int c0 = col[e] * 2;
        float4 a0 = q4[c0], a1 = q4[c0 + 1];
        s0.x += a0.x; s0.y += a0.y; s0.z += a0.z; s0.w += a0.w;
        s1.x += a1.x; s1.y += a1.y; s1.z += a1.z; s1.w += a1.w;
    }
    s0.x += __shfl_xor(s0.x, 1, 64); s0.y += __shfl_xor(s0.y, 1, 64);
    s0.z += __shfl_xor(s0.z, 1, 64); s0.w += __shfl_xor(s0.w, 1, 64);
    s1.x += __shfl_xor(s1.x, 1, 64); s1.y += __shfl_xor(s1.y, 1, 64);
    s1.z += __shfl_xor(s1.z, 1, 64); s1.w += __shfl_xor(s1.w, 1, 64);
    float dn = dinv[n];
    float h[8] = { s0.x * dn, s0.y * dn, s0.z * dn, s0.w * dn,
                   s1.x * dn, s1.y * dn, s1.z * dn, s1.w * dn };
    int f0 = half * 4;
    if (qout) {
        float4 qv = make_float4(h[f0] * dn, h[f0 + 1] * dn, h[f0 + 2] * dn, h[f0 + 3] * dn);
        ((float4*)qout)[n * 2 + half] = qv;
    }
    if (Wa) {
        float4 o = ((float4*)outa)[n * 2 + half];
        float av[4] = { o.x, o.y, o.z, o.w };
        #pragma unroll
        for (int j = 0; j < 8; ++j) {
            float hv = h[j];
            #pragma unroll
            for (int f = 0; f < 4; ++f) av[f] += hv * Wa[j * 8 + f0 + f];
        }
        if (fina) {
            #pragma unroll
            for (int f = 0; f < 4; ++f) av[f] = fmaxf(av[f] + ba[f0 + f], 0.f);
        }
        ((float4*)outa)[n * 2 + half] = make_float4(av[0], av[1], av[2], av[3]);
    }
    {
        float4 o = ((float4*)outb)[n * 2 + half];
        float bv[4] = { o.x, o.y, o.z, o.w };
        #pragma unroll
        for (int j = 0; j < 8; ++j) {
            float hv = h[j];
            #pragma unroll
            for (int f = 0; f < 4; ++f) bv[f] += hv * Wb[j * 8 + f0 + f];
        }
        if (finb) {
            #pragma unroll
            for (int f = 0; f < 4; ++f) bv[f] = fmaxf(bv[f] + bb[f0 + f], 0.f);
        }
        ((float4*)outb)[n * 2 + half] = make_float4(bv[0], bv[1], bv[2], bv[3]);
    }
}

// scalar sym-prop Horner step, q-prescaled input (1 load/edge).
// writes qout[n*qstride] = dinv*v (non-final) or fout[n] = relu(v+bias) (final)
__global__ void k_symprop1n(const float* __restrict__ qin, const float* __restrict__ yk,
                            const int* __restrict__ row_start, const int* __restrict__ deg,
                            const float* __restrict__ dinv, const int* __restrict__ col,
                            float* __restrict__ qout, int qstride,
                            float* __restrict__ fout, const float* __restrict__ bias) {
    int t = blockIdx.x * TPB + threadIdx.x;
    if (t >= NN * 4) return;
    int n = t >> 2, qd = t & 3;
    int rs = row_start[n], d = deg[n];
    float s = 0.f;
    for (int e = rs + qd; e < rs + d; e += 4) s += qin[col[e]];
    s += __shfl_xor(s, 1, 64);
    s += __shfl_xor(s, 2, 64);
    if (qd == 0) {
        float dn = dinv[n];
        float v = dn * s + yk[n];
        if (fout) fout[n] = fmaxf(v + bias[0], 0.f);
        else      qout[(size_t)n * qstride] = dn * v;
    }
}

// fused 2-channel sym-prop Horner step (a-chain paired with b-chain), float2 loads
__global__ void k_symprop2(const float* __restrict__ q2in, const float* __restrict__ yka,
                           const float* __restrict__ ykb, const int* __restrict__ row_start,
                           const int* __restrict__ deg, const float* __restrict__ dinv,
                           const int* __restrict__ col, float* __restrict__ q2out,
                           float* __restrict__ fa, float* __restrict__ fb,
                           const float* __restrict__ biasa, const float* __restrict__ biasb) {
    int t = blockIdx.x * TPB + threadIdx.x;
    if (t >= NN * 4) return;
    int n = t >> 2, qd = t & 3;
    int rs = row_start[n], d = deg[n];
    const float2* q2 = (const float2*)q2in;
    float sa = 0.f, sb = 0.f;
    for (int e = rs + qd; e < rs + d; e += 4) {
        float2 v = q2[col[e]];
        sa += v.x; sb += v.y;
    }
    sa += __shfl_xor(sa, 1, 64); sa += __shfl_xor(sa, 2, 64);
    sb += __shfl_xor(sb, 1, 64); sb += __shfl_xor(sb, 2, 64);
    if (qd == 0) {
        float dn = dinv[n];
        float va = dn * sa + yka[n];
        float vb = dn * sb + ykb[n];
        if (fa) {
            fa[n] = fmaxf(va + biasa[0], 0.f);
            fb[n] = fmaxf(vb + biasb[0], 0.f);
        } else {
            ((float2*)q2out)[n] = make_float2(dn * va, dn * vb);
        }
    }
}

// mean scalar propagation + SAGE3 epilogue
__global__ void k_sage3(const float* __restrict__ yl, const float* __restrict__ yr,
                        const int* __restrict__ row_start, const int* __restrict__ deg,
                        const float* __restrict__ inv_deg, const int* __restrict__ col,
                        const float* __restrict__ b3, float* __restrict__ x1f) {
    int t = blockIdx.x * TPB + threadIdx.x;
    if (t >= NN * 4) return;
    int n = t >> 2, q = t & 3;
    int rs = row_start[n], d = deg[n];
    float s = 0.f;
    for (int e = rs + q; e < rs + d; e += 4) s += yl[col[e]];
    s += __shfl_xor(s, 1, 64);
    s += __shfl_xor(s, 2, 64);
    if (q == 0) x1f[n] = fmaxf(s * inv_deg[n] + yr[n] + b3[0], 0.f);
}

// ---------------------------------------------------------------- dense transforms
// SAGE1: x1 = relu(a8@W1l + x@W1r + b1), K=8
__global__ void k_sage1(const float* __restrict__ a8, const float* __restrict__ x,
                        const float* __restrict__ W1l, const float* __restrict__ W1r,
                        const float* __restrict__ b1, float* __restrict__ x1) {
    int t = blockIdx.x * TPB + threadIdx.x;
    if (t >= NN * 16) return;
    int n = t >> 4, og = (t & 15) * 8;
    float acc[8];
    #pragma unroll
    for (int j = 0; j < 8; ++j) acc[j] = b1[og + j];
    const float* ar = a8 + (size_t)n * 8;
    const float* xr = x + (size_t)n * 8;
    #pragma unroll
    for (int k = 0; k < 8; ++k) {
        float av = ar[k], xv = xr[k];
        const float4* wl = (const float4*)(W1l + k * 128 + og);
        const float4* wr = (const float4*)(W1r + k * 128 + og);
        float4 l0 = wl[0], l1 = wl[1], r0 = wr[0], r1 = wr[1];
        acc[0] += av * l0.x + xv * r0.x;
        acc[1] += av * l0.y + xv * r0.y;
        acc[2] += av * l0.z + xv * r0.z;
        acc[3] += av * l0.w + xv * r0.w;
        acc[4] += av * l1.x + xv * r1.x;
        acc[5] += av * l1.y + xv * r1.y;
        acc[6] += av * l1.z + xv * r1.z;
        acc[7] += av * l1.w + xv * r1.w;
    }
    #pragma unroll
    for (int j = 0; j < 8; ++j)
        x1[(size_t)n * 128 + og + j] = fmaxf(acc[j], 0.f);
}

// SAGE2: x1b = relu(a128@W2l + x1@W2r + b2); weights staged in LDS (32-K tiles),
// 4 nodes x 8 outs per thread, 64 nodes x 128 outs per block
__global__ __launch_bounds__(256) void k_sage2(const float* __restrict__ a128,
                        const float* __restrict__ x1,
                        const float* __restrict__ W2l, const float* __restrict__ W2r,
                        const float* __restrict__ b2, float* __restrict__ x1b) {
    __shared__ float wl[32 * 128];
    __shared__ float wr[32 * 128];
    int tid = threadIdx.x;
    int og = (tid & 15) * 8;
    int n0 = blockIdx.x * 64 + (tid >> 4) * 4;
    int n[4];
    #pragma unroll
    for (int i = 0; i < 4; ++i) n[i] = min(n0 + i, NN - 1);
    const float4* A[4];
    const float4* X[4];
    #pragma unroll
    for (int i = 0; i < 4; ++i) {
        A[i] = (const float4*)(a128 + (size_t)n[i] * 128);
        X[i] = (const float4*)(x1 + (size_t)n[i] * 128);
    }
    float acc[4][8];
    #pragma unroll
    for (int i = 0; i < 4; ++i)
        #pragma unroll
        for (int j = 0; j < 8; ++j) acc[i][j] = b2[og + j];

    for (int kt = 0; kt < 128; kt += 32) {
        if (kt) __syncthreads();
        const float4* gl = (const float4*)(W2l + kt * 128);
        const float4* gr = (const float4*)(W2r + kt * 128);
        #pragma unroll
        for (int i = 0; i < 4; ++i) {
            ((float4*)wl)[tid + i * 256] = gl[tid + i * 256];
            ((float4*)wr)[tid + i * 256] = gr[tid + i * 256];
        }
        __syncthreads();
        #pragma unroll
        for (int k4 = 0; k4 < 8; ++k4) {
            float av[4][4], xv[4][4];
            #pragma unroll
            for (int i = 0; i < 4; ++i) {
                *(float4*)av[i] = A[i][kt / 4 + k4];
                *(float4*)xv[i] = X[i][kt / 4 + k4];
            }
            #pragma unroll
            for (int r = 0; r < 4; ++r) {
                float4 w0 = *(const float4*)(wl + (k4 * 4 + r) * 128 + og);
                float4 w1 = *(const float4*)(wl + (k4 * 4 + r) * 128 + og + 4);
                float4 u0 = *(const float4*)(wr + (k4 * 4 + r) * 128 + og);
                float4 u1 = *(const float4*)(wr + (k4 * 4 + r) * 128 + og + 4);
                #pragma unroll
                for (int i = 0; i < 4; ++i) {
                    float a = av[i][r], xs = xv[i][r];
                    acc[i][0] += a * w0.x + xs * u0.x;
                    acc[i][1] += a * w0.y + xs * u0.y;
                    acc[i][2] += a * w0.z + xs * u0.z;
                    acc[i][3] += a * w0.w + xs * u0.w;
                    acc[i][4] += a * w1.x + xs * u1.x;
                    acc[i][5] += a * w1.y + xs * u1.y;
                    acc[i][6] += a * w1.z + xs * u1.z;
                    acc[i][7] += a * w1.w + xs * u1.w;
                }
            }
        }
    }
    #pragma unroll
    for (int i = 0; i < 4; ++i) {
        if (n0 + i < NN) {
            float4 o0 = make_float4(fmaxf(acc[i][0], 0.f), fmaxf(acc[i][1], 0.f),
                                    fmaxf(acc[i][2], 0.f), fmaxf(acc[i][3], 0.f));
            float4 o1 = make_float4(fmaxf(acc[i][4], 0.f), fmaxf(acc[i][5], 0.f),
                                    fmaxf(acc[i][6], 0.f), fmaxf(acc[i][7], 0.f));
            *(float4*)(x1b + (size_t)n[i] * 128 + og) = o0;
            *(float4*)(x1b + (size_t)n[i] * 128 + og + 4) = o1;
        }
    }
}

// SAGE3 pre-multiply: yl = x1b@W3l, yr = x1b@W3r (wave per node)
__global__ void k_dots(const float* __restrict__ x1b, const float* __restrict__ W3l,
                       const float* __restrict__ W3r, float* __restrict__ yl,
                       float* __restrict__ yr) {
    int t = blockIdx.x * TPB + threadIdx.x;
    if (t >= NN * 64) return;
    int n = t >> 6, l = t & 63;
    float v0 = x1b[(size_t)n * 128 + l];
    float v1 = x1b[(size_t)n * 128 + 64 + l];
    float pl = v0 * W3l[l] + v1 * W3l[64 + l];
    float pr = v0 * W3r[l] + v1 * W3r[64 + l];
    #pragma unroll
    for (int o = 1; o < 64; o <<= 1) {
        pl += __shfl_xor(pl, o, 64);
        pr += __shfl_xor(pr, o, 64);
    }
    if (l == 0) { yl[n] = pl; yr[n] = pr; }
}

// TAG k=0 term for both branches + q0 = dinv[n]*x[n]
__global__ void k_taginit(const float* __restrict__ x, const float* __restrict__ TaW,
                          const float* __restrict__ TbW, const float* __restrict__ dinv,
                          float* __restrict__ outa, float* __restrict__ outb,
                          float* __restrict__ q0) {
    int t = blockIdx.x * TPB + threadIdx.x;
    if (t >= NN * 8) return;
    int n = t >> 3, o = t & 7;
    const float* xr = x + (size_t)n * 8;
    float sa = 0.f, sb = 0.f;
    #pragma unroll
    for (int j = 0; j < 8; ++j) {
        float v = xr[j];
        sa += v * TaW[j * 8 + o];
        sb += v * TbW[j * 8 + o];
    }
    outa[t] = sa;
    outb[t] = sb;
    q0[t] = xr[o] * dinv[n];
}

// project 8-wide feats through K1 (8x1) matrices; last k is written pre-scaled
// by dinv into qlast[n*qstride] (Horner seed), others into y[k*NN+n]
__global__ void k_tag2proj(const float* __restrict__ h8, const float* __restrict__ W,
                           float* __restrict__ y, int K1, const float* __restrict__ dinv,
                           float* __restrict__ qlast, int qstride) {
    int n = blockIdx.x * TPB + threadIdx.x;
    if (n >= NN) return;
    float hr[8];
    #pragma unroll
    for (int j = 0; j < 8; ++j) hr[j] = h8[(size_t)n * 8 + j];
    for (int k = 0; k < K1; ++k) {
        float s = 0.f;
        #pragma unroll
        for (int j = 0; j < 8; ++j) s += hr[j] * W[k * 8 + j];
        if (k == K1 - 1) qlast[(size_t)n * qstride] = s * dinv[n];
        else             y[(size_t)k * NN + n] = s;
    }
}

// final combine
__global__ void k_final(const float* __restrict__ x1f, const float* __restrict__ x2s,
                        const float* __restrict__ x3s, const float* __restrict__ l2w,
                        const float* __restrict__ l2b, const float* __restrict__ l1w,
                        const float* __restrict__ l1b, float* __restrict__ out) {
    int n = blockIdx.x * TPB + threadIdx.x;
    if (n >= NN) return;
    float x23 = fmaxf(x2s[n] * l2w[0] + x3s[n] * l2w[1] + l2b[0], 0.f);
    out[n] = fmaxf(x1f[n] * l1w[0] + x23 * l1w[1] + l1b[0], 0.f);
}

// ---------------------------------------------------------------- host launch
#define GL(kern, n, ...) \
    kern<<<dim3((unsigned)(((long)(n) + TPB - 1) / TPB)), dim3(TPB), 0, stream>>>(__VA_ARGS__)

extern "C" void kernel_launch(void* const* d_in, const int* in_sizes, int n_in,
                              void* d_out, int out_size, void* d_ws, size_t ws_size,
                              hipStream_t stream) {
    (void)in_sizes; (void)n_in; (void)out_size; (void)ws_size;
    const float* x   = (const float*)d_in[0];
    const int*   ei  = (const int*)d_in[1];
    const int*   src = ei;
    const int*   dst = ei + NE;
    const float* W1l = (const float*)d_in[2];
    const float* W1r = (const float*)d_in[3];
    const float* b1  = (const float*)d_in[4];
    const float* W2l = (const float*)d_in[5];
    const float* W2r = (const float*)d_in[6];
    const float* b2  = (const float*)d_in[7];
    const float* W3l = (const float*)d_in[8];
    const float* W3r = (const float*)d_in[9];
    const float* b3  = (const float*)d_in[10];
    const float* TaW1 = (const float*)d_in[11];
    const float* TaB1 = (const float*)d_in[12];
    const float* TaW2 = (const float*)d_in[13];
    const float* TaB2 = (const float*)d_in[14];
    const float* TbW1 = (const float*)d_in[15];
    const float* TbB1 = (const float*)d_in[16];
    const float* TbW2 = (const float*)d_in[17];
    const float* TbB2 = (const float*)d_in[18];
    const float* l2w = (const float*)d_in[19];
    const float* l2b = (const float*)d_in[20];
    const float* l1w = (const float*)d_in[21];
    const float* l1b = (const float*)d_in[22];
    float* out = (float*)d_out;

    char* p = (char*)d_ws;
    size_t off = 0;
    auto alloc = [&](size_t bytes) -> void* {
        void* r = p + off;
        off = (off + bytes + 255) & ~(size_t)255;
        return r;
    };
    int*   deg       = (int*)  alloc((size_t)NN * 4);
    float* inv_deg   = (float*)alloc((size_t)NN * 4);
    float* dinv      = (float*)alloc((size_t)NN * 4);
    int*   row_start = (int*)  alloc((size_t)NN * 4);
    int*   cursor    = (int*)  alloc((size_t)NN * 4);
    int*   counter   = (int*)  alloc(256);
    int*   col       = (int*)  alloc((size_t)NE * 4);
    float* a8        = (float*)alloc((size_t)NN * 8 * 4);
    float* qA        = (float*)alloc((size_t)NN * 8 * 4);
    float* qB        = (float*)alloc((size_t)NN * 8 * 4);
    float* outa      = (float*)alloc((size_t)NN * 8 * 4);
    float* outb      = (float*)alloc((size_t)NN * 8 * 4);
    float* x1        = (float*)alloc((size_t)NN * 128 * 4);
    float* a128      = (float*)alloc((size_t)NN * 128 * 4);
    float* x1b       = (float*)alloc((size_t)NN * 128 * 4);
    float* yl        = (float*)alloc((size_t)NN * 4);
    float* yr        = (float*)alloc((size_t)NN * 4);
    float* x1f       = (float*)alloc((size_t)NN * 4);
    float* x2s       = (float*)alloc((size_t)NN * 4);
    float* x3s       = (float*)alloc((size_t)NN * 4);
    float* tA        = (float*)alloc((size_t)NN * 4);
    float* tB        = (float*)alloc((size_t)NN * 4);
    float* qb0       = (float*)alloc((size_t)NN * 4);
    float* q2a       = (float*)alloc((size_t)NN * 8);
    float* q2b       = (float*)alloc((size_t)NN * 8);
    float* ya        = (float*)alloc((size_t)NN * 4 * 4);
    float* yb        = (float*)alloc((size_t)NN * 10 * 4);

    // CSR build (reused by all edge passes)
    GL(k_init, NN, deg, cursor, counter);
    GL(k_deg, NE, dst, deg);
    GL(k_prep, NN, deg, inv_deg, dinv, row_start, counter);
    GL(k_fill, NE, src, dst, row_start, cursor, col);

    // SAGE1
    GL(k_meanprop8, (long)NN * 2, x, row_start, deg, inv_deg, col, a8);
    GL(k_sage1, (long)NN * 16, a8, x, W1l, W1r, b1, x1);
    // SAGE2
    GL(k_meanprop128, (long)NN * 32, x1, row_start, deg, inv_deg, col, a128);
    k_sage2<<<dim3((NN + 63) / 64), dim3(256), 0, stream>>>(a128, x1, W2l, W2r, b2, x1b);
    // SAGE3 (pre-multiplied scalar propagation)
    GL(k_dots, (long)NN * 64, x1b, W3l, W3r, yl, yr);
    GL(k_sage3, (long)NN * 4, yl, yr, row_start, deg, inv_deg, col, b3, x1f);

    // TAG layer 1 — shared P^k x chain, q-prescaled, fused projections
    GL(k_taginit, (long)NN * 8, x, TaW1, TbW1, dinv, outa, outb, qA);
    {
        float* qcur = qA;
        float* qnext = qB;
        for (int k = 1; k <= 9; ++k) {
            float* qout = (k < 9) ? qnext : nullptr;
            const float* Wa = (k <= 3) ? (TaW1 + (size_t)k * 64) : nullptr;
            GL(k_tagstep, (long)NN * 2, qcur, row_start, deg, dinv, col, qout,
               Wa, TbW1 + (size_t)k * 64, outa, outb, TaB1, TbB1,
               (k == 3) ? 1 : 0, (k == 9) ? 1 : 0);
            if (qout) { float* tmp = qcur; qcur = qnext; qnext = tmp; }
        }
    }

    // TAG layer 2 projections (last k written pre-scaled as Horner seed)
    GL(k_tag2proj, NN, outa, TaW2, ya, 4, dinv, q2a, 2);       // a seed -> q2a[2n]
    GL(k_tag2proj, NN, outb, TbW2, yb, 10, dinv, qb0, 1);      // b seed -> qb0

    // TAGb solo Horner steps 1..6 (yk = yb[8]..yb[3]); step 6 lands in q2a[2n+1]
    GL(k_symprop1n, (long)NN * 4, qb0, yb + 8 * NN, row_start, deg, dinv, col, tA, 1, (float*)nullptr, (const float*)nullptr);
    GL(k_symprop1n, (long)NN * 4, tA,  yb + 7 * NN, row_start, deg, dinv, col, tB, 1, (float*)nullptr, (const float*)nullptr);
    GL(k_symprop1n, (long)NN * 4, tB,  yb + 6 * NN, row_start, deg, dinv, col, tA, 1, (float*)nullptr, (const float*)nullptr);
    GL(k_symprop1n, (long)NN * 4, tA,  yb + 5 * NN, row_start, deg, dinv, col, tB, 1, (float*)nullptr, (const float*)nullptr);
    GL(k_symprop1n, (long)NN * 4, tB,  yb + 4 * NN, row_start, deg, dinv, col, tA, 1, (float*)nullptr, (const float*)nullptr);
    GL(k_symprop1n, (long)NN * 4, tA,  yb + 3 * NN, row_start, deg, dinv, col, q2a + 1, 2, (float*)nullptr, (const float*)nullptr);

    // fused a+b Horner steps (float2): q2a -> q2b -> q2a -> finals
    GL(k_symprop2, (long)NN * 4, q2a, ya + 2 * NN, yb + 2 * NN, row_start, deg, dinv, col, q2b,
       (float*)nullptr, (float*)nullptr, (const float*)nullptr, (const float*)nullptr);
    GL(k_symprop2, (long)NN * 4, q2b, ya + 1 * NN, yb + 1 * NN, row_start, deg, dinv, col, q2a,
       (float*)nullptr, (float*)nullptr, (const float*)nullptr, (const float*)nullptr);
    GL(k_symprop2, (long)NN * 4, q2a, ya + 0 * NN, yb + 0 * NN, row_start, deg, dinv, col, (float*)nullptr,
       x2s, x3s, TaB2, TbB2);

    // final combine
    GL(k_final, NN, x1f, x2s, x3s, l2w, l2b, l1w, l1b, out);
}

// Round 4
// 854.193 us; speedup vs baseline: 1.7693x; 1.1183x over previous
//
#include <hip/hip_runtime.h>

#define NN 100000
#define NE 1600000
#define TPB 256

// ---------------------------------------------------------------- CSR build
__global__ void k_init(int* __restrict__ deg, int* __restrict__ cursor, int* __restrict__ counter) {
    int i = blockIdx.x * TPB + threadIdx.x;
    if (i < NN) { deg[i] = 0; cursor[i] = 0; }
    if (i == 0) counter[0] = 0;
}

__global__ void k_deg(const int* __restrict__ dst, int* __restrict__ deg) {
    int e = blockIdx.x * TPB + threadIdx.x;
    if (e < NE) atomicAdd(&deg[dst[e]], 1);
}

__global__ void k_prep(const int* __restrict__ deg, float* __restrict__ inv_deg,
                       float* __restrict__ dinv, int* __restrict__ row_start,
                       int* __restrict__ counter) {
    int i = blockIdx.x * TPB + threadIdx.x;
    if (i < NN) {
        int d = deg[i];
        inv_deg[i] = d > 0 ? 1.0f / (float)d : 0.0f;
        dinv[i]    = d > 0 ? 1.0f / sqrtf((float)d) : 0.0f;
        row_start[i] = atomicAdd(counter, d);
    }
}

__global__ void k_fill(const int* __restrict__ src, const int* __restrict__ dst,
                       const int* __restrict__ row_start, int* __restrict__ cursor,
                       int* __restrict__ col) {
    int e = blockIdx.x * TPB + threadIdx.x;
    if (e < NE) {
        int d = dst[e];
        int p = atomicAdd(&cursor[d], 1);
        col[row_start[d] + p] = src[e];
    }
}

// ---------------------------------------------------------------- propagation
// mean aggregation, 8 feats: 2 threads per node, float4 gathers, shfl combine
__global__ void k_meanprop8(const float* __restrict__ h, const int* __restrict__ row_start,
                            const int* __restrict__ deg, const float* __restrict__ inv_deg,
                            const int* __restrict__ col, float* __restrict__ out) {
    int t = blockIdx.x * TPB + threadIdx.x;
    if (t >= NN * 2) return;
    int n = t >> 1, half = t & 1;
    int rs = row_start[n], end = rs + deg[n];
    const float4* h4 = (const float4*)h;
    float4 s0 = make_float4(0,0,0,0), s1 = make_float4(0,0,0,0);
    int e = rs + half;
    for (; e + 2 < end; e += 4) {
        int c0 = col[e] * 2, c1 = col[e + 2] * 2;
        float4 a0 = h4[c0], a1 = h4[c0 + 1], b0 = h4[c1], b1 = h4[c1 + 1];
        s0.x += a0.x + b0.x; s0.y += a0.y + b0.y; s0.z += a0.z + b0.z; s0.w += a0.w + b0.w;
        s1.x += a1.x + b1.x; s1.y += a1.y + b1.y; s1.z += a1.z + b1.z; s1.w += a1.w + b1.w;
    }
    if (e < end) {
        int c0 = col[e] * 2;
        float4 a0 = h4[c0], a1 = h4[c0 + 1];
        s0.x += a0.x; s0.y += a0.y; s0.z += a0.z; s0.w += a0.w;
        s1.x += a1.x; s1.y += a1.y; s1.z += a1.z; s1.w += a1.w;
    }
    s0.x += __shfl_xor(s0.x, 1, 64); s0.y += __shfl_xor(s0.y, 1, 64);
    s0.z += __shfl_xor(s0.z, 1, 64); s0.w += __shfl_xor(s0.w, 1, 64);
    s1.x += __shfl_xor(s1.x, 1, 64); s1.y += __shfl_xor(s1.y, 1, 64);
    s1.z += __shfl_xor(s1.z, 1, 64); s1.w += __shfl_xor(s1.w, 1, 64);
    float w = inv_deg[n];
    float4 o = (half == 0) ? s0 : s1;
    o.x *= w; o.y *= w; o.z *= w; o.w *= w;
    ((float4*)out)[n * 2 + half] = o;
}

// mean aggregation, 128 feats: thread per (node, 4 feats), float4 gather
__global__ void k_meanprop128(const float* __restrict__ h, const int* __restrict__ row_start,
                              const int* __restrict__ deg, const float* __restrict__ inv_deg,
                              const int* __restrict__ col, float* __restrict__ out) {
    int t = blockIdx.x * TPB + threadIdx.x;
    if (t >= NN * 32) return;
    int n = t >> 5, f4 = t & 31;
    int rs = row_start[n], d = deg[n];
    const float4* h4 = (const float4*)h;
    float4 s = make_float4(0.f, 0.f, 0.f, 0.f);
    for (int e = rs; e < rs + d; ++e) {
        int c = col[e];
        float4 v = h4[(size_t)c * 32 + f4];
        s.x += v.x; s.y += v.y; s.z += v.z; s.w += v.w;
    }
    float w = inv_deg[n];
    s.x *= w; s.y *= w; s.z *= w; s.w *= w;
    ((float4*)out)[t] = s;
}

// fused TAG layer-1 step: 2 threads/node, q-prescaled gather (q = dinv[n]*h[n]),
// writes q_next and accumulates projections h@Wa / h@Wb into outa/outb.
__global__ void k_tagstep(const float* __restrict__ q, const int* __restrict__ row_start,
                          const int* __restrict__ deg, const float* __restrict__ dinv,
                          const int* __restrict__ col, float* __restrict__ qout,
                          const float* __restrict__ Wa, const float* __restrict__ Wb,
                          float* __restrict__ outa, float* __restrict__ outb,
                          const float* __restrict__ ba, const float* __restrict__ bb,
                          int fina, int finb) {
    int t = blockIdx.x * TPB + threadIdx.x;
    if (t >= NN * 2) return;
    int n = t >> 1, half = t & 1;
    int rs = row_start[n], end = rs + deg[n];
    const float4* q4 = (const float4*)q;
    float4 s0 = make_float4(0,0,0,0), s1 = make_float4(0,0,0,0);
    int e = rs + half;
    for (; e + 2 < end; e += 4) {
        int c0 = col[e] * 2, c1 = col[e + 2] * 2;
        float4 a0 = q4[c0], a1 = q4[c0 + 1], b0 = q4[c1], b1 = q4[c1 + 1];
        s0.x += a0.x + b0.x; s0.y += a0.y + b0.y; s0.z += a0.z + b0.z; s0.w += a0.w + b0.w;
        s1.x += a1.x + b1.x; s1.y += a1.y + b1.y; s1.z += a1.z + b1.z; s1.w += a1.w + b1.w;
    }
    if (e < end) {
        int c0 = col[e] * 2;
        float4 a0 = q4[c0], a1 = q4[c0 + 1];
        s0.x += a0.x; s0.y += a0.y; s0.z += a0.z; s0.w += a0.w;
        s1.x += a1.x; s1.y += a1.y; s1.z += a1.z; s1.w += a1.w;
    }
    s0.x += __shfl_xor(s0.x, 1, 64); s0.y += __shfl_xor(s0.y, 1, 64);
    s0.z += __shfl_xor(s0.z, 1, 64); s0.w += __shfl_xor(s0.w, 1, 64);
    s1.x += __shfl_xor(s1.x, 1, 64); s1.y += __shfl_xor(s1.y, 1, 64);
    s1.z += __shfl_xor(s1.z, 1, 64); s1.w += __shfl_xor(s1.w, 1, 64);
    float dn = dinv[n];
    float h[8] = { s0.x * dn, s0.y * dn, s0.z * dn, s0.w * dn,
                   s1.x * dn, s1.y * dn, s1.z * dn, s1.w * dn };
    int f0 = half * 4;
    if (qout) {
        float4 qv = make_float4(h[f0] * dn, h[f0 + 1] * dn, h[f0 + 2] * dn, h[f0 + 3] * dn);
        ((float4*)qout)[n * 2 + half] = qv;
    }
    if (Wa) {
        float4 o = ((float4*)outa)[n * 2 + half];
        float av[4] = { o.x, o.y, o.z, o.w };
        #pragma unroll
        for (int j = 0; j < 8; ++j) {
            float hv = h[j];
            #pragma unroll
            for (int f = 0; f < 4; ++f) av[f] += hv * Wa[j * 8 + f0 + f];
        }
        if (fina) {
            #pragma unroll
            for (int f = 0; f < 4; ++f) av[f] = fmaxf(av[f] + ba[f0 + f], 0.f);
        }
        ((float4*)outa)[n * 2 + half] = make_float4(av[0], av[1], av[2], av[3]);
    }
    {
        float4 o = ((float4*)outb)[n * 2 + half];
        float bv[4] = { o.x, o.y, o.z, o.w };
        #pragma unroll
        for (int j = 0; j < 8; ++j) {
            float hv = h[j];
            #pragma unroll
            for (int f = 0; f < 4; ++f) bv[f] += hv * Wb[j * 8 + f0 + f];
        }
        if (finb) {
            #pragma unroll
            for (int f = 0; f < 4; ++f) bv[f] = fmaxf(bv[f] + bb[f0 + f], 0.f);
        }
        ((float4*)outb)[n * 2 + half] = make_float4(bv[0], bv[1], bv[2], bv[3]);
    }
}

// scalar sym-prop Horner step, q-prescaled input (1 load/edge).
__global__ void k_symprop1n(const float* __restrict__ qin, const float* __restrict__ yk,
                            const int* __restrict__ row_start, const int* __restrict__ deg,
                            const float* __restrict__ dinv, const int* __restrict__ col,
                            float* __restrict__ qout, int qstride,
                            float* __restrict__ fout, const float* __restrict__ bias) {
    int t = blockIdx.x * TPB + threadIdx.x;
    if (t >= NN * 4) return;
    int n = t >> 2, qd = t & 3;
    int rs = row_start[n], d = deg[n];
    float s = 0.f;
    for (int e = rs + qd; e < rs + d; e += 4) s += qin[col[e]];
    s += __shfl_xor(s, 1, 64);
    s += __shfl_xor(s, 2, 64);
    if (qd == 0) {
        float dn = dinv[n];
        float v = dn * s + yk[n];
        if (fout) fout[n] = fmaxf(v + bias[0], 0.f);
        else      qout[(size_t)n * qstride] = dn * v;
    }
}

// fused 2-channel sym-prop Horner step (a-chain paired with b-chain), float2 loads
__global__ void k_symprop2(const float* __restrict__ q2in, const float* __restrict__ yka,
                           const float* __restrict__ ykb, const int* __restrict__ row_start,
                           const int* __restrict__ deg, const float* __restrict__ dinv,
                           const int* __restrict__ col, float* __restrict__ q2out,
                           float* __restrict__ fa, float* __restrict__ fb,
                           const float* __restrict__ biasa, const float* __restrict__ biasb) {
    int t = blockIdx.x * TPB + threadIdx.x;
    if (t >= NN * 4) return;
    int n = t >> 2, qd = t & 3;
    int rs = row_start[n], d = deg[n];
    const float2* q2 = (const float2*)q2in;
    float sa = 0.f, sb = 0.f;
    for (int e = rs + qd; e < rs + d; e += 4) {
        float2 v = q2[col[e]];
        sa += v.x; sb += v.y;
    }
    sa += __shfl_xor(sa, 1, 64); sa += __shfl_xor(sa, 2, 64);
    sb += __shfl_xor(sb, 1, 64); sb += __shfl_xor(sb, 2, 64);
    if (qd == 0) {
        float dn = dinv[n];
        float va = dn * sa + yka[n];
        float vb = dn * sb + ykb[n];
        if (fa) {
            fa[n] = fmaxf(va + biasa[0], 0.f);
            fb[n] = fmaxf(vb + biasb[0], 0.f);
        } else {
            ((float2*)q2out)[n] = make_float2(dn * va, dn * vb);
        }
    }
}

// mean scalar propagation + SAGE3 epilogue
__global__ void k_sage3(const float* __restrict__ yl, const float* __restrict__ yr,
                        const int* __restrict__ row_start, const int* __restrict__ deg,
                        const float* __restrict__ inv_deg, const int* __restrict__ col,
                        const float* __restrict__ b3, float* __restrict__ x1f) {
    int t = blockIdx.x * TPB + threadIdx.x;
    if (t >= NN * 4) return;
    int n = t >> 2, q = t & 3;
    int rs = row_start[n], d = deg[n];
    float s = 0.f;
    for (int e = rs + q; e < rs + d; e += 4) s += yl[col[e]];
    s += __shfl_xor(s, 1, 64);
    s += __shfl_xor(s, 2, 64);
    if (q == 0) x1f[n] = fmaxf(s * inv_deg[n] + yr[n] + b3[0], 0.f);
}

// ---------------------------------------------------------------- dense transforms
// SAGE1: x1 = relu(a8@W1l + x@W1r + b1), K=8 (row-major out, feeds the gather)
__global__ void k_sage1(const float* __restrict__ a8, const float* __restrict__ x,
                        const float* __restrict__ W1l, const float* __restrict__ W1r,
                        const float* __restrict__ b1, float* __restrict__ x1) {
    int t = blockIdx.x * TPB + threadIdx.x;
    if (t >= NN * 16) return;
    int n = t >> 4, og = (t & 15) * 8;
    float acc[8];
    #pragma unroll
    for (int j = 0; j < 8; ++j) acc[j] = b1[og + j];
    const float* ar = a8 + (size_t)n * 8;
    const float* xr = x + (size_t)n * 8;
    #pragma unroll
    for (int k = 0; k < 8; ++k) {
        float av = ar[k], xv = xr[k];
        const float4* wl = (const float4*)(W1l + k * 128 + og);
        const float4* wr = (const float4*)(W1r + k * 128 + og);
        float4 l0 = wl[0], l1 = wl[1], r0 = wr[0], r1 = wr[1];
        acc[0] += av * l0.x + xv * r0.x;
        acc[1] += av * l0.y + xv * r0.y;
        acc[2] += av * l0.z + xv * r0.z;
        acc[3] += av * l0.w + xv * r0.w;
        acc[4] += av * l1.x + xv * r1.x;
        acc[5] += av * l1.y + xv * r1.y;
        acc[6] += av * l1.z + xv * r1.z;
        acc[7] += av * l1.w + xv * r1.w;
    }
    #pragma unroll
    for (int j = 0; j < 8; ++j)
        x1[(size_t)n * 128 + og + j] = fmaxf(acc[j], 0.f);
}

// transpose [NN][128] -> [128][NN] via LDS tile (64 nodes per block);
// grid.y picks which of the two buffers to transpose
__global__ __launch_bounds__(256) void k_transpose(const float* __restrict__ in0,
        float* __restrict__ out0, const float* __restrict__ in1, float* __restrict__ out1) {
    const float* in = blockIdx.y ? in1 : in0;
    float* outp = blockIdx.y ? out1 : out0;
    __shared__ float t[128][65];
    int n0 = blockIdx.x * 64;
    int tid = threadIdx.x;
    #pragma unroll
    for (int i = 0; i < 8; ++i) {
        int idx = tid + i * 256;          // 0..2047 over (64 nodes x 32 f4)
        int nl = idx >> 5;
        int kq = (idx & 31) << 2;
        int n = n0 + nl;
        float4 v = (n < NN) ? *(const float4*)(in + (size_t)n * 128 + kq)
                            : make_float4(0.f, 0.f, 0.f, 0.f);
        t[kq][nl] = v.x; t[kq + 1][nl] = v.y; t[kq + 2][nl] = v.z; t[kq + 3][nl] = v.w;
    }
    __syncthreads();
    #pragma unroll
    for (int i = 0; i < 8; ++i) {
        int idx = tid + i * 256;          // 0..2047 over (128 k x 16 n-quads)
        int k = idx >> 4;
        int nq = (idx & 15) << 2;
        if (n0 + nq + 3 < NN) {
            float4 v = make_float4(t[k][nq], t[k][nq + 1], t[k][nq + 2], t[k][nq + 3]);
            *(float4*)(outp + (size_t)k * NN + n0 + nq) = v;
        }
    }
}

// SAGE2, transposed operands: lane = node, 32 outputs in registers,
// weights wave-uniform (SGPR broadcast). x1bT[j][n] output.
__global__ __launch_bounds__(256) void k_sage2t(const float* __restrict__ aT,
        const float* __restrict__ xT, const float* __restrict__ W2l,
        const float* __restrict__ W2r, const float* __restrict__ b2,
        float* __restrict__ oT) {
    int n0 = blockIdx.x * 256 + threadIdx.x;
    int n = (n0 < NN) ? n0 : (NN - 1);
    int og = blockIdx.y * 32;
    float acc[32];
    #pragma unroll
    for (int j = 0; j < 32; ++j) acc[j] = b2[og + j];
    const float* ap = aT + n;
    const float* xp = xT + n;
    const float* wlp = W2l + og;
    const float* wrp = W2r + og;
    #pragma unroll 2
    for (int k = 0; k < 128; ++k) {
        float a = ap[0], xv = xp[0];
        ap += NN; xp += NN;
        const float4* wl4 = (const float4*)(wlp + (k << 7));
        const float4* wr4 = (const float4*)(wrp + (k << 7));
        #pragma unroll
        for (int q = 0; q < 8; ++q) {
            float4 wl = wl4[q], wr = wr4[q];
            acc[q * 4 + 0] += a * wl.x + xv * wr.x;
            acc[q * 4 + 1] += a * wl.y + xv * wr.y;
            acc[q * 4 + 2] += a * wl.z + xv * wr.z;
            acc[q * 4 + 3] += a * wl.w + xv * wr.w;
        }
    }
    if (n0 < NN) {
        float* op = oT + (size_t)og * NN + n0;
        #pragma unroll
        for (int j = 0; j < 32; ++j) {
            op[0] = fmaxf(acc[j], 0.f);
            op += NN;
        }
    }
}

// SAGE3 pre-multiply from transposed x1bT: yl[n] = x1bT[:,n]·W3l, yr likewise.
// lane = node, fully coalesced, weights uniform.
__global__ void k_dotsT(const float* __restrict__ oT, const float* __restrict__ W3l,
                        const float* __restrict__ W3r, float* __restrict__ yl,
                        float* __restrict__ yr) {
    int n = blockIdx.x * TPB + threadIdx.x;
    if (n >= NN) return;
    const float* p = oT + n;
    float pl = 0.f, pr = 0.f;
    #pragma unroll 4
    for (int k = 0; k < 128; ++k) {
        float v = p[0];
        p += NN;
        pl += v * W3l[k];
        pr += v * W3r[k];
    }
    yl[n] = pl;
    yr[n] = pr;
}

// TAG k=0 term for both branches + q0 = dinv[n]*x[n]
__global__ void k_taginit(const float* __restrict__ x, const float* __restrict__ TaW,
                          const float* __restrict__ TbW, const float* __restrict__ dinv,
                          float* __restrict__ outa, float* __restrict__ outb,
                          float* __restrict__ q0) {
    int t = blockIdx.x * TPB + threadIdx.x;
    if (t >= NN * 8) return;
    int n = t >> 3, o = t & 7;
    const float* xr = x + (size_t)n * 8;
    float sa = 0.f, sb = 0.f;
    #pragma unroll
    for (int j = 0; j < 8; ++j) {
        float v = xr[j];
        sa += v * TaW[j * 8 + o];
        sb += v * TbW[j * 8 + o];
    }
    outa[t] = sa;
    outb[t] = sb;
    q0[t] = xr[o] * dinv[n];
}

// project 8-wide feats through K1 (8x1) matrices; last k pre-scaled by dinv
__global__ void k_tag2proj(const float* __restrict__ h8, const float* __restrict__ W,
                           float* __restrict__ y, int K1, const float* __restrict__ dinv,
                           float* __restrict__ qlast, int qstride) {
    int n = blockIdx.x * TPB + threadIdx.x;
    if (n >= NN) return;
    float hr[8];
    #pragma unroll
    for (int j = 0; j < 8; ++j) hr[j] = h8[(size_t)n * 8 + j];
    for (int k = 0; k < K1; ++k) {
        float s = 0.f;
        #pragma unroll
        for (int j = 0; j < 8; ++j) s += hr[j] * W[k * 8 + j];
        if (k == K1 - 1) qlast[(size_t)n * qstride] = s * dinv[n];
        else             y[(size_t)k * NN + n] = s;
    }
}

// final combine
__global__ void k_final(const float* __restrict__ x1f, const float* __restrict__ x2s,
                        const float* __restrict__ x3s, const float* __restrict__ l2w,
                        const float* __restrict__ l2b, const float* __restrict__ l1w,
                        const float* __restrict__ l1b, float* __restrict__ out) {
    int n = blockIdx.x * TPB + threadIdx.x;
    if (n >= NN) return;
    float x23 = fmaxf(x2s[n] * l2w[0] + x3s[n] * l2w[1] + l2b[0], 0.f);
    out[n] = fmaxf(x1f[n] * l1w[0] + x23 * l1w[1] + l1b[0], 0.f);
}

// ---------------------------------------------------------------- host launch
#define GL(kern, n, ...) \
    kern<<<dim3((unsigned)(((long)(n) + TPB - 1) / TPB)), dim3(TPB), 0, stream>>>(__VA_ARGS__)

extern "C" void kernel_launch(void* const* d_in, const int* in_sizes, int n_in,
                              void* d_out, int out_size, void* d_ws, size_t ws_size,
                              hipStream_t stream) {
    (void)in_sizes; (void)n_in; (void)out_size; (void)ws_size;
    const float* x   = (const float*)d_in[0];
    const int*   ei  = (const int*)d_in[1];
    const int*   src = ei;
    const int*   dst = ei + NE;
    const float* W1l = (const float*)d_in[2];
    const float* W1r = (const float*)d_in[3];
    const float* b1  = (const float*)d_in[4];
    const float* W2l = (const float*)d_in[5];
    const float* W2r = (const float*)d_in[6];
    const float* b2  = (const float*)d_in[7];
    const float* W3l = (const float*)d_in[8];
    const float* W3r = (const float*)d_in[9];
    const float* b3  = (const float*)d_in[10];
    const float* TaW1 = (const float*)d_in[11];
    const float* TaB1 = (const float*)d_in[12];
    const float* TaW2 = (const float*)d_in[13];
    const float* TaB2 = (const float*)d_in[14];
    const float* TbW1 = (const float*)d_in[15];
    const float* TbB1 = (const float*)d_in[16];
    const float* TbW2 = (const float*)d_in[17];
    const float* TbB2 = (const float*)d_in[18];
    const float* l2w = (const float*)d_in[19];
    const float* l2b = (const float*)d_in[20];
    const float* l1w = (const float*)d_in[21];
    const float* l1b = (const float*)d_in[22];
    float* out = (float*)d_out;

    char* p = (char*)d_ws;
    size_t off = 0;
    auto alloc = [&](size_t bytes) -> void* {
        void* r = p + off;
        off = (off + bytes + 255) & ~(size_t)255;
        return r;
    };
    int*   deg       = (int*)  alloc((size_t)NN * 4);
    float* inv_deg   = (float*)alloc((size_t)NN * 4);
    float* dinv      = (float*)alloc((size_t)NN * 4);
    int*   row_start = (int*)  alloc((size_t)NN * 4);
    int*   cursor    = (int*)  alloc((size_t)NN * 4);
    int*   counter   = (int*)  alloc(256);
    int*   col       = (int*)  alloc((size_t)NE * 4);
    float* a8        = (float*)alloc((size_t)NN * 8 * 4);
    float* qA        = (float*)alloc((size_t)NN * 8 * 4);
    float* qB        = (float*)alloc((size_t)NN * 8 * 4);
    float* outa      = (float*)alloc((size_t)NN * 8 * 4);
    float* outb      = (float*)alloc((size_t)NN * 8 * 4);
    float* x1        = (float*)alloc((size_t)NN * 128 * 4);
    float* a128      = (float*)alloc((size_t)NN * 128 * 4);   // row-major temp; reused as x1bT
    float* a128T     = (float*)alloc((size_t)NN * 128 * 4);
    float* x1T       = (float*)alloc((size_t)NN * 128 * 4);
    float* yl        = (float*)alloc((size_t)NN * 4);
    float* yr        = (float*)alloc((size_t)NN * 4);
    float* x1f       = (float*)alloc((size_t)NN * 4);
    float* x2s       = (float*)alloc((size_t)NN * 4);
    float* x3s       = (float*)alloc((size_t)NN * 4);
    float* tA        = (float*)alloc((size_t)NN * 4);
    float* tB        = (float*)alloc((size_t)NN * 4);
    float* qb0       = (float*)alloc((size_t)NN * 4);
    float* q2a       = (float*)alloc((size_t)NN * 8);
    float* q2b       = (float*)alloc((size_t)NN * 8);
    float* ya        = (float*)alloc((size_t)NN * 4 * 4);
    float* yb        = (float*)alloc((size_t)NN * 10 * 4);
    float* x1bT      = a128;   // a128 (row-major) dead once a128T exists

    // CSR build (reused by all edge passes)
    GL(k_init, NN, deg, cursor, counter);
    GL(k_deg, NE, dst, deg);
    GL(k_prep, NN, deg, inv_deg, dinv, row_start, counter);
    GL(k_fill, NE, src, dst, row_start, cursor, col);

    // SAGE1
    GL(k_meanprop8, (long)NN * 2, x, row_start, deg, inv_deg, col, a8);
    GL(k_sage1, (long)NN * 16, a8, x, W1l, W1r, b1, x1);
    // SAGE2: aggregate, transpose both operands, GEMM in transposed layout
    GL(k_meanprop128, (long)NN * 32, x1, row_start, deg, inv_deg, col, a128);
    k_transpose<<<dim3((NN + 63) / 64, 2), dim3(256), 0, stream>>>(a128, a128T, x1, x1T);
    k_sage2t<<<dim3((NN + 255) / 256, 4), dim3(256), 0, stream>>>(a128T, x1T, W2l, W2r, b2, x1bT);
    // SAGE3 (pre-multiplied scalar propagation)
    GL(k_dotsT, NN, x1bT, W3l, W3r, yl, yr);
    GL(k_sage3, (long)NN * 4, yl, yr, row_start, deg, inv_deg, col, b3, x1f);

    // TAG layer 1 — shared P^k x chain, q-prescaled, fused projections
    GL(k_taginit, (long)NN * 8, x, TaW1, TbW1, dinv, outa, outb, qA);
    {
        float* qcur = qA;
        float* qnext = qB;
        for (int k = 1; k <= 9; ++k) {
            float* qout = (k < 9) ? qnext : nullptr;
            const float* Wa = (k <= 3) ? (TaW1 + (size_t)k * 64) : nullptr;
            GL(k_tagstep, (long)NN * 2, qcur, row_start, deg, dinv, col, qout,
               Wa, TbW1 + (size_t)k * 64, outa, outb, TaB1, TbB1,
               (k == 3) ? 1 : 0, (k == 9) ? 1 : 0);
            if (qout) { float* tmp = qcur; qcur = qnext; qnext = tmp; }
        }
    }

    // TAG layer 2 projections (last k written pre-scaled as Horner seed)
    GL(k_tag2proj, NN, outa, TaW2, ya, 4, dinv, q2a, 2);       // a seed -> q2a[2n]
    GL(k_tag2proj, NN, outb, TbW2, yb, 10, dinv, qb0, 1);      // b seed -> qb0

    // TAGb solo Horner steps 1..6; step 6 lands in q2a[2n+1]
    GL(k_symprop1n, (long)NN * 4, qb0, yb + 8 * NN, row_start, deg, dinv, col, tA, 1, (float*)nullptr, (const float*)nullptr);
    GL(k_symprop1n, (long)NN * 4, tA,  yb + 7 * NN, row_start, deg, dinv, col, tB, 1, (float*)nullptr, (const float*)nullptr);
    GL(k_symprop1n, (long)NN * 4, tB,  yb + 6 * NN, row_start, deg, dinv, col, tA, 1, (float*)nullptr, (const float*)nullptr);
    GL(k_symprop1n, (long)NN * 4, tA,  yb + 5 * NN, row_start, deg, dinv, col, tB, 1, (float*)nullptr, (const float*)nullptr);
    GL(k_symprop1n, (long)NN * 4, tB,  yb + 4 * NN, row_start, deg, dinv, col, tA, 1, (float*)nullptr, (const float*)nullptr);
    GL(k_symprop1n, (long)NN * 4, tA,  yb + 3 * NN, row_start, deg, dinv, col, q2a + 1, 2, (float*)nullptr, (const float*)nullptr);

    // fused a+b Horner steps (float2): q2a -> q2b -> q2a -> finals
    GL(k_symprop2, (long)NN * 4, q2a, ya + 2 * NN, yb + 2 * NN, row_start, deg, dinv, col, q2b,
       (float*)nullptr, (float*)nullptr, (const float*)nullptr, (const float*)nullptr);
    GL(k_symprop2, (long)NN * 4, q2b, ya + 1 * NN, yb + 1 * NN, row_start, deg, dinv, col, q2a,
       (float*)nullptr, (float*)nullptr, (const float*)nullptr, (const float*)nullptr);
    GL(k_symprop2, (long)NN * 4, q2a, ya + 0 * NN, yb + 0 * NN, row_start, deg, dinv, col, (float*)nullptr,
       x2s, x3s, TaB2, TbB2);

    // final combine
    GL(k_final, NN, x1f, x2s, x3s, l2w, l2b, l1w, l1b, out);
}